// Round 3
// baseline (97.342 us; speedup 1.0000x reference)
//
#include <hip/hip_runtime.h>
#include <hip/hip_cooperative_groups.h>

namespace cg = cooperative_groups;

#define B 4
#define N 512
#define HID 64
#define HEADS 4
#define DH 16
#define SCALE 0.25f
#define NEG (-1e9f)
#define LN_EPS 1e-5f

constexpr int ROWS = B * N;                       // 2048
constexpr size_t OFF_ST  = 0;
constexpr size_t OFF_Q   = (size_t)ROWS * HID;    // 131072 floats
constexpr size_t OFF_K   = 2 * OFF_Q;
constexpr size_t OFF_V   = 3 * OFF_Q;
constexpr size_t OFF_MSG = 4 * OFF_Q;             // total ws use: 2.62 MB

constexpr int NBLK = 256;                         // == CU count; 80KB LDS -> co-resident

// ---------------------------------------------------------------------------
// One cooperative kernel, three phases separated by grid.sync():
//   P1 proj:  blk -> 8 rows;  ST=x@W1+b1, Q=x@W3+b3, K=x@W4+b4, V=x@W2+b2
//   P2 attn:  blk -> (it,h,b) 32-row tile, K/V staged in LDS, online softmax
//   P3 LN:    blk -> 8 rows;  out = LN(x + ST + MSG)
// ---------------------------------------------------------------------------
__global__ __launch_bounds__(256, 1) void fused_kernel(
    const float* __restrict__ x,
    const int*   __restrict__ adj,
    const float* __restrict__ efeat,
    const float* __restrict__ W1w, const float* __restrict__ W1b,
    const float* __restrict__ W2w, const float* __restrict__ W2b,
    const float* __restrict__ W3w, const float* __restrict__ W3b,
    const float* __restrict__ W4w, const float* __restrict__ W4b,
    const float* __restrict__ W5w, const float* __restrict__ W5b,
    const float* __restrict__ lng, const float* __restrict__ lnb,
    float* __restrict__ ws, float* __restrict__ out)
{
  cg::grid_group grid = cg::this_grid();
  __shared__ float smem[2 * N * 20];               // 80 KB, phase-aliased

  const int t = threadIdx.x;
  const int blk = blockIdx.x;

  // ======================= Phase 1: projections ============================
  {
    float* xsT = smem;                             // [64][8]
    const int rows0 = blk * 8;
    if (t < 128) {
      const float4 v = *(const float4*)&x[(size_t)rows0 * HID + t * 4];
      const int r = t >> 4;
      const int k0 = (t & 15) * 4;
      xsT[(k0 + 0) * 8 + r] = v.x;
      xsT[(k0 + 1) * 8 + r] = v.y;
      xsT[(k0 + 2) * 8 + r] = v.z;
      xsT[(k0 + 3) * 8 + r] = v.w;
    }
    __syncthreads();

    const int m = t >> 6;                          // one W matrix per wave
    const int c = t & 63;
    const float* Ww; const float* Wb; size_t off;
    if      (m == 0) { Ww = W1w; Wb = W1b; off = OFF_ST; }
    else if (m == 1) { Ww = W3w; Wb = W3b; off = OFF_Q;  }
    else if (m == 2) { Ww = W4w; Wb = W4b; off = OFF_K;  }
    else             { Ww = W2w; Wb = W2b; off = OFF_V;  }

    float acc[8];
#pragma unroll
    for (int r = 0; r < 8; ++r) acc[r] = 0.f;

#pragma unroll 16
    for (int k = 0; k < 64; ++k) {
      const float w = Ww[(k << 6) + c];            // coalesced per wave
      const float* xr = &xsT[k * 8];               // wave-uniform -> broadcast
      const float4 a0 = *(const float4*)(xr);
      const float4 a1 = *(const float4*)(xr + 4);
      acc[0] = fmaf(a0.x, w, acc[0]); acc[1] = fmaf(a0.y, w, acc[1]);
      acc[2] = fmaf(a0.z, w, acc[2]); acc[3] = fmaf(a0.w, w, acc[3]);
      acc[4] = fmaf(a1.x, w, acc[4]); acc[5] = fmaf(a1.y, w, acc[5]);
      acc[6] = fmaf(a1.z, w, acc[6]); acc[7] = fmaf(a1.w, w, acc[7]);
    }

    const float bias = Wb[c];
    const size_t base = off + (size_t)rows0 * HID + c;
#pragma unroll
    for (int r = 0; r < 8; ++r)
      ws[base + (size_t)r * HID] = acc[r] + bias;
  }

  grid.sync();

  // ======================= Phase 2: attention ==============================
  {
    float* Ksh = smem;                             // [512][20]  40 KB
    float* Vsh = smem + N * 20;                    // [512][20]  40 KB

    const int it = blk & 15;
    const int h  = (blk >> 4) & 3;
    const int b  = blk >> 6;
    const int g  = t & 15;
    const int il = t >> 4;
    const int i0 = it * 32;
    const int iA = i0 + il;
    const int iB = iA + 16;

    const float* Qb = ws + OFF_Q;
    const float* Kb = ws + OFF_K;
    const float* Vb = ws + OFF_V;
    float* msg = ws + OFF_MSG;

    {  // stage K,V head-slices into LDS
      const int jj = t >> 2;
      const int dq = (t & 3) << 2;
#pragma unroll
      for (int p = 0; p < 8; ++p) {
        const int j = jj + (p << 6);
        const size_t gb = ((size_t)(b * N + j)) * HID + h * DH + dq;
        *(float4*)&Ksh[j * 20 + dq] = *(const float4*)&Kb[gb];
        *(float4*)&Vsh[j * 20 + dq] = *(const float4*)&Vb[gb];
      }
    }

    const float4 w50 = *(const float4*)&W5w[h * DH];
    const float4 w51 = *(const float4*)&W5w[h * DH + 4];
    const float4 w52 = *(const float4*)&W5w[h * DH + 8];
    const float4 w53 = *(const float4*)&W5w[h * DH + 12];
    const float4 b50 = *(const float4*)&W5b[h * DH];
    const float4 b51 = *(const float4*)&W5b[h * DH + 4];
    const float4 b52 = *(const float4*)&W5b[h * DH + 8];
    const float4 b53 = *(const float4*)&W5b[h * DH + 12];

    float4 qA0, qA1, qA2, qA3, qB0, qB1, qB2, qB3;
    float qw5A, qb5A, qw5B, qb5B;
    {
      const float* qr = Qb + ((size_t)(b * N + iA)) * HID + h * DH;
      qA0 = *(const float4*)(qr);     qA1 = *(const float4*)(qr + 4);
      qA2 = *(const float4*)(qr + 8); qA3 = *(const float4*)(qr + 12);
      qw5A = qA0.x*w50.x + qA0.y*w50.y + qA0.z*w50.z + qA0.w*w50.w
           + qA1.x*w51.x + qA1.y*w51.y + qA1.z*w51.z + qA1.w*w51.w
           + qA2.x*w52.x + qA2.y*w52.y + qA2.z*w52.z + qA2.w*w52.w
           + qA3.x*w53.x + qA3.y*w53.y + qA3.z*w53.z + qA3.w*w53.w;
      qb5A = qA0.x*b50.x + qA0.y*b50.y + qA0.z*b50.z + qA0.w*b50.w
           + qA1.x*b51.x + qA1.y*b51.y + qA1.z*b51.z + qA1.w*b51.w
           + qA2.x*b52.x + qA2.y*b52.y + qA2.z*b52.z + qA2.w*b52.w
           + qA3.x*b53.x + qA3.y*b53.y + qA3.z*b53.z + qA3.w*b53.w;
    }
    {
      const float* qr = Qb + ((size_t)(b * N + iB)) * HID + h * DH;
      qB0 = *(const float4*)(qr);     qB1 = *(const float4*)(qr + 4);
      qB2 = *(const float4*)(qr + 8); qB3 = *(const float4*)(qr + 12);
      qw5B = qB0.x*w50.x + qB0.y*w50.y + qB0.z*w50.z + qB0.w*w50.w
           + qB1.x*w51.x + qB1.y*w51.y + qB1.z*w51.z + qB1.w*w51.w
           + qB2.x*w52.x + qB2.y*w52.y + qB2.z*w52.z + qB2.w*w52.w
           + qB3.x*w53.x + qB3.y*w53.y + qB3.z*w53.z + qB3.w*w53.w;
      qb5B = qB0.x*b50.x + qB0.y*b50.y + qB0.z*b50.z + qB0.w*b50.w
           + qB1.x*b51.x + qB1.y*b51.y + qB1.z*b51.z + qB1.w*b51.w
           + qB2.x*b52.x + qB2.y*b52.y + qB2.z*b52.z + qB2.w*b52.w
           + qB3.x*b53.x + qB3.y*b53.y + qB3.z*b53.z + qB3.w*b53.w;
    }

    __syncthreads();

    const int*   adjA = adj   + ((size_t)(b * N + iA)) * N;
    const int*   adjB = adj   + ((size_t)(b * N + iB)) * N;
    const float* eA   = efeat + ((size_t)(b * N + iA)) * N;
    const float* eB   = efeat + ((size_t)(b * N + iB)) * N;

    float mA = -3.0e38f, lA = 0.f, mB = -3.0e38f, lB = 0.f;
    float accA[16], accB[16];
#pragma unroll
    for (int d = 0; d < 16; ++d) { accA[d] = 0.f; accB[d] = 0.f; }

    int   aAv = adjA[g], aBv = adjB[g];
    float eAv = eA[g],   eBv = eB[g];

    for (int jj = 0; jj < 32; ++jj) {
      const int j = g + (jj << 4);
      const int jn = (j + 16) & (N - 1);          // wrapped prefetch
      const int   naA = adjA[jn], naB = adjB[jn];
      const float neA = eA[jn],   neB = eB[jn];

      const float* kr = &Ksh[j * 20];
      const float4 k0 = *(const float4*)(kr);
      const float4 k1 = *(const float4*)(kr + 4);
      const float4 k2 = *(const float4*)(kr + 8);
      const float4 k3 = *(const float4*)(kr + 12);

      float sA = qA0.x*k0.x + qA0.y*k0.y + qA0.z*k0.z + qA0.w*k0.w;
      sA = fmaf(qA1.x,k1.x, fmaf(qA1.y,k1.y, fmaf(qA1.z,k1.z, fmaf(qA1.w,k1.w, sA))));
      sA = fmaf(qA2.x,k2.x, fmaf(qA2.y,k2.y, fmaf(qA2.z,k2.z, fmaf(qA2.w,k2.w, sA))));
      sA = fmaf(qA3.x,k3.x, fmaf(qA3.y,k3.y, fmaf(qA3.z,k3.z, fmaf(qA3.w,k3.w, sA))));
      float sB = qB0.x*k0.x + qB0.y*k0.y + qB0.z*k0.z + qB0.w*k0.w;
      sB = fmaf(qB1.x,k1.x, fmaf(qB1.y,k1.y, fmaf(qB1.z,k1.z, fmaf(qB1.w,k1.w, sB))));
      sB = fmaf(qB2.x,k2.x, fmaf(qB2.y,k2.y, fmaf(qB2.z,k2.z, fmaf(qB2.w,k2.w, sB))));
      sB = fmaf(qB3.x,k3.x, fmaf(qB3.y,k3.y, fmaf(qB3.z,k3.z, fmaf(qB3.w,k3.w, sB))));

      float s0 = (sA + eAv * qw5A + qb5A) * SCALE;
      float s1 = (sB + eBv * qw5B + qb5B) * SCALE;
      s0 = (aAv == 0) ? NEG : s0;
      s1 = (aBv == 0) ? NEG : s1;

      float pA, pB;
      if (s0 > mA) {
        const float sc = __expf(mA - s0);
        lA *= sc;
#pragma unroll
        for (int d = 0; d < 16; ++d) accA[d] *= sc;
        mA = s0; pA = 1.f;
      } else pA = __expf(s0 - mA);
      lA += pA;
      if (s1 > mB) {
        const float sc = __expf(mB - s1);
        lB *= sc;
#pragma unroll
        for (int d = 0; d < 16; ++d) accB[d] *= sc;
        mB = s1; pB = 1.f;
      } else pB = __expf(s1 - mB);
      lB += pB;

      const float* vr = &Vsh[j * 20];
      const float4 v0 = *(const float4*)(vr);
      const float4 v1 = *(const float4*)(vr + 4);
      const float4 v2 = *(const float4*)(vr + 8);
      const float4 v3 = *(const float4*)(vr + 12);
      accA[0] = fmaf(pA,v0.x,accA[0]); accA[1] = fmaf(pA,v0.y,accA[1]);
      accA[2] = fmaf(pA,v0.z,accA[2]); accA[3] = fmaf(pA,v0.w,accA[3]);
      accA[4] = fmaf(pA,v1.x,accA[4]); accA[5] = fmaf(pA,v1.y,accA[5]);
      accA[6] = fmaf(pA,v1.z,accA[6]); accA[7] = fmaf(pA,v1.w,accA[7]);
      accA[8] = fmaf(pA,v2.x,accA[8]); accA[9] = fmaf(pA,v2.y,accA[9]);
      accA[10]= fmaf(pA,v2.z,accA[10]);accA[11]= fmaf(pA,v2.w,accA[11]);
      accA[12]= fmaf(pA,v3.x,accA[12]);accA[13]= fmaf(pA,v3.y,accA[13]);
      accA[14]= fmaf(pA,v3.z,accA[14]);accA[15]= fmaf(pA,v3.w,accA[15]);
      accB[0] = fmaf(pB,v0.x,accB[0]); accB[1] = fmaf(pB,v0.y,accB[1]);
      accB[2] = fmaf(pB,v0.z,accB[2]); accB[3] = fmaf(pB,v0.w,accB[3]);
      accB[4] = fmaf(pB,v1.x,accB[4]); accB[5] = fmaf(pB,v1.y,accB[5]);
      accB[6] = fmaf(pB,v1.z,accB[6]); accB[7] = fmaf(pB,v1.w,accB[7]);
      accB[8] = fmaf(pB,v2.x,accB[8]); accB[9] = fmaf(pB,v2.y,accB[9]);
      accB[10]= fmaf(pB,v2.z,accB[10]);accB[11]= fmaf(pB,v2.w,accB[11]);
      accB[12]= fmaf(pB,v3.x,accB[12]);accB[13]= fmaf(pB,v3.y,accB[13]);
      accB[14]= fmaf(pB,v3.z,accB[14]);accB[15]= fmaf(pB,v3.w,accB[15]);

      aAv = naA; aBv = naB; eAv = neA; eBv = neB;
    }

    // cross-g combine per row
    float MA = mA, MB = mB;
#pragma unroll
    for (int o = 1; o < 16; o <<= 1) {
      MA = fmaxf(MA, __shfl_xor(MA, o, 16));
      MB = fmaxf(MB, __shfl_xor(MB, o, 16));
    }
    const float wA = __expf(mA - MA);
    const float wB = __expf(mB - MB);
    float lwA = lA * wA, lwB = lB * wB;
#pragma unroll
    for (int o = 1; o < 16; o <<= 1) {
      lwA += __shfl_xor(lwA, o, 16);
      lwB += __shfl_xor(lwB, o, 16);
    }

    // transpose-reduce weighted accumulators through LDS (reuse Ksh region)
    __syncthreads();
    float* P = Ksh;
    const int baseA = (il * 16 + g) * 20;
    const int baseB = ((il + 16) * 16 + g) * 20;
    *(float4*)&P[baseA+ 0] = make_float4(accA[0]*wA, accA[1]*wA, accA[2]*wA, accA[3]*wA);
    *(float4*)&P[baseA+ 4] = make_float4(accA[4]*wA, accA[5]*wA, accA[6]*wA, accA[7]*wA);
    *(float4*)&P[baseA+ 8] = make_float4(accA[8]*wA, accA[9]*wA, accA[10]*wA,accA[11]*wA);
    *(float4*)&P[baseA+12] = make_float4(accA[12]*wA,accA[13]*wA,accA[14]*wA,accA[15]*wA);
    *(float4*)&P[baseB+ 0] = make_float4(accB[0]*wB, accB[1]*wB, accB[2]*wB, accB[3]*wB);
    *(float4*)&P[baseB+ 4] = make_float4(accB[4]*wB, accB[5]*wB, accB[6]*wB, accB[7]*wB);
    *(float4*)&P[baseB+ 8] = make_float4(accB[8]*wB, accB[9]*wB, accB[10]*wB,accB[11]*wB);
    *(float4*)&P[baseB+12] = make_float4(accB[12]*wB,accB[13]*wB,accB[14]*wB,accB[15]*wB);
    __syncthreads();

    float sA2 = 0.f, sB2 = 0.f;
#pragma unroll
    for (int gp = 0; gp < 16; ++gp) {
      sA2 += P[(il * 16 + gp) * 20 + g];
      sB2 += P[((il + 16) * 16 + gp) * 20 + g];
    }
    msg[((size_t)(b * N + iA)) * HID + h * DH + g] = sA2 * (1.0f / lwA);
    msg[((size_t)(b * N + iB)) * HID + h * DH + g] = sB2 * (1.0f / lwB);
  }

  grid.sync();

  // ======================= Phase 3: residual + LayerNorm ===================
  {
    const int lane = t & 63;
    const int w = t >> 6;
    const float* ST  = ws + OFF_ST;
    const float* MSG = ws + OFF_MSG;
#pragma unroll
    for (int rr = 0; rr < 2; ++rr) {
      const int row = blk * 8 + w * 2 + rr;
      const size_t idx = (size_t)row * HID + lane;
      const float v = x[idx] + ST[idx] + MSG[idx];
      float mu = v;
#pragma unroll
      for (int o = 1; o < 64; o <<= 1) mu += __shfl_xor(mu, o, 64);
      mu *= (1.0f / 64.0f);
      const float dv = v - mu;
      float var = dv * dv;
#pragma unroll
      for (int o = 1; o < 64; o <<= 1) var += __shfl_xor(var, o, 64);
      var *= (1.0f / 64.0f);
      out[idx] = dv * rsqrtf(var + LN_EPS) * lng[lane] + lnb[lane];
    }
  }
}

// ---------------------------------------------------------------------------
extern "C" void kernel_launch(void* const* d_in, const int* in_sizes, int n_in,
                              void* d_out, int out_size, void* d_ws, size_t ws_size,
                              hipStream_t stream)
{
  const float* x   = (const float*)d_in[0];
  const int*   adj = (const int*)d_in[1];
  const float* ef  = (const float*)d_in[2];
  const float* W1w = (const float*)d_in[3];
  const float* W1b = (const float*)d_in[4];
  const float* W2w = (const float*)d_in[5];
  const float* W2b = (const float*)d_in[6];
  const float* W3w = (const float*)d_in[7];
  const float* W3b = (const float*)d_in[8];
  const float* W4w = (const float*)d_in[9];
  const float* W4b = (const float*)d_in[10];
  const float* W5w = (const float*)d_in[11];
  const float* W5b = (const float*)d_in[12];
  const float* lng = (const float*)d_in[13];
  const float* lnb = (const float*)d_in[14];
  float* ws  = (float*)d_ws;
  float* out = (float*)d_out;

  void* args[] = { (void*)&x, (void*)&adj, (void*)&ef,
                   (void*)&W1w, (void*)&W1b, (void*)&W2w, (void*)&W2b,
                   (void*)&W3w, (void*)&W3b, (void*)&W4w, (void*)&W4b,
                   (void*)&W5w, (void*)&W5b, (void*)&lng, (void*)&lnb,
                   (void*)&ws, (void*)&out };
  hipLaunchCooperativeKernel((const void*)fused_kernel, dim3(NBLK), dim3(256),
                             args, 0, stream);
}

// Round 4
// 24.003 us; speedup vs baseline: 4.0554x; 4.0554x over previous
//
#include <hip/hip_runtime.h>

#define B 4
#define N 512
#define HID 64
#define HEADS 4
#define DH 16
#define SCALE 0.25f
#define NEG (-1e9f)
#define LN_EPS 1e-5f

constexpr int ROWS = B * N;                       // 2048
constexpr size_t OFF_ST  = 0;
constexpr size_t OFF_Q   = (size_t)ROWS * HID;    // 131072 floats
constexpr size_t OFF_K   = 2 * OFF_Q;
constexpr size_t OFF_V   = 3 * OFF_Q;
constexpr size_t OFF_MSG = 4 * OFF_Q;             // total ws use: 2.62 MB

// ---------------------------------------------------------------------------
// Kernel A: fused projections. ST=x@W1+b1, Q=x@W3+b3, K=x@W4+b4, V=x@W2+b2
// ---------------------------------------------------------------------------
__global__ __launch_bounds__(256) void proj_kernel(
    const float* __restrict__ x,
    const float* __restrict__ W1w, const float* __restrict__ W1b,
    const float* __restrict__ W2w, const float* __restrict__ W2b,
    const float* __restrict__ W3w, const float* __restrict__ W3b,
    const float* __restrict__ W4w, const float* __restrict__ W4b,
    float* __restrict__ ws)
{
  __shared__ float xsT[64 * 8];      // [k][r]
  const int t = threadIdx.x;
  const int rows0 = blockIdx.x * 8;

  if (t < 128) {
    const float4 v = *(const float4*)&x[(size_t)rows0 * HID + t * 4];
    const int r = t >> 4;
    const int k0 = (t & 15) * 4;
    xsT[(k0 + 0) * 8 + r] = v.x;
    xsT[(k0 + 1) * 8 + r] = v.y;
    xsT[(k0 + 2) * 8 + r] = v.z;
    xsT[(k0 + 3) * 8 + r] = v.w;
  }
  __syncthreads();

  const int m = t >> 6;
  const int c = t & 63;
  const float* Ww; const float* Wb; size_t off;
  if      (m == 0) { Ww = W1w; Wb = W1b; off = OFF_ST; }
  else if (m == 1) { Ww = W3w; Wb = W3b; off = OFF_Q;  }
  else if (m == 2) { Ww = W4w; Wb = W4b; off = OFF_K;  }
  else             { Ww = W2w; Wb = W2b; off = OFF_V;  }

  float acc[8];
#pragma unroll
  for (int r = 0; r < 8; ++r) acc[r] = 0.f;

#pragma unroll 16
  for (int k = 0; k < 64; ++k) {
    const float w = Ww[(k << 6) + c];
    const float* xr = &xsT[k * 8];
    const float4 a0 = *(const float4*)(xr);
    const float4 a1 = *(const float4*)(xr + 4);
    acc[0] = fmaf(a0.x, w, acc[0]); acc[1] = fmaf(a0.y, w, acc[1]);
    acc[2] = fmaf(a0.z, w, acc[2]); acc[3] = fmaf(a0.w, w, acc[3]);
    acc[4] = fmaf(a1.x, w, acc[4]); acc[5] = fmaf(a1.y, w, acc[5]);
    acc[6] = fmaf(a1.z, w, acc[6]); acc[7] = fmaf(a1.w, w, acc[7]);
  }

  const float bias = Wb[c];
  const size_t base = off + (size_t)rows0 * HID + c;
#pragma unroll
  for (int r = 0; r < 8; ++r)
    ws[base + (size_t)r * HID] = acc[r] + bias;
}

// ---------------------------------------------------------------------------
// Kernel B v3: two-pass softmax, scores in registers (no serial online chain).
// grid (32,4,4) x 256 thr = (b, h, 16-row i-tile); 80KB LDS -> 2 blocks/CU.
// Thread (il,g): row i = it*16+il, j = g + 16*jj, jj = 0..31 fully unrolled.
// ---------------------------------------------------------------------------
__global__ __launch_bounds__(256, 2) void attn_kernel(
    const int*   __restrict__ adj,
    const float* __restrict__ efeat,
    const float* __restrict__ W5w, const float* __restrict__ W5b,
    float* __restrict__ ws)
{
  __shared__ float Ksh[N * 20];     // 40 KB, stride-20 rows: conflict-free b128
  __shared__ float Vsh[N * 20];     // 40 KB

  const int it = blockIdx.x, h = blockIdx.y, b = blockIdx.z;
  const int t = threadIdx.x;
  const int g  = t & 15;
  const int il = t >> 4;
  const int i  = it * 16 + il;

  const float* Qb = ws + OFF_Q;
  const float* Kb = ws + OFF_K;
  const float* Vb = ws + OFF_V;
  float* msg = ws + OFF_MSG;

  {  // stage K,V head-slices into LDS
    const int jj = t >> 2;
    const int dq = (t & 3) << 2;
#pragma unroll
    for (int p = 0; p < 8; ++p) {
      const int j = jj + (p << 6);
      const size_t gb = ((size_t)(b * N + j)) * HID + h * DH + dq;
      *(float4*)&Ksh[j * 20 + dq] = *(const float4*)&Kb[gb];
      *(float4*)&Vsh[j * 20 + dq] = *(const float4*)&Vb[gb];
    }
  }

  // Q fragment + edge scalars
  const float* qrow = Qb + ((size_t)(b * N + i)) * HID + h * DH;
  const float4 q0 = *(const float4*)(qrow);
  const float4 q1 = *(const float4*)(qrow + 4);
  const float4 q2 = *(const float4*)(qrow + 8);
  const float4 q3 = *(const float4*)(qrow + 12);
  const float4 w50 = *(const float4*)&W5w[h * DH];
  const float4 w51 = *(const float4*)&W5w[h * DH + 4];
  const float4 w52 = *(const float4*)&W5w[h * DH + 8];
  const float4 w53 = *(const float4*)&W5w[h * DH + 12];
  const float4 b50 = *(const float4*)&W5b[h * DH];
  const float4 b51 = *(const float4*)&W5b[h * DH + 4];
  const float4 b52 = *(const float4*)&W5b[h * DH + 8];
  const float4 b53 = *(const float4*)&W5b[h * DH + 12];
  const float qw5 = q0.x*w50.x + q0.y*w50.y + q0.z*w50.z + q0.w*w50.w
                  + q1.x*w51.x + q1.y*w51.y + q1.z*w51.z + q1.w*w51.w
                  + q2.x*w52.x + q2.y*w52.y + q2.z*w52.z + q2.w*w52.w
                  + q3.x*w53.x + q3.y*w53.y + q3.z*w53.z + q3.w*w53.w;
  const float qb5 = q0.x*b50.x + q0.y*b50.y + q0.z*b50.z + q0.w*b50.w
                  + q1.x*b51.x + q1.y*b51.y + q1.z*b51.z + q1.w*b51.w
                  + q2.x*b52.x + q2.y*b52.y + q2.z*b52.z + q2.w*b52.w
                  + q3.x*b53.x + q3.y*b53.y + q3.z*b53.z + q3.w*b53.w;

  __syncthreads();

  const int*   adjRow = adj   + ((size_t)(b * N + i)) * N;
  const float* eRow   = efeat + ((size_t)(b * N + i)) * N;

  // ---- pass 1: all 32 masked scores into registers (independent work) ----
  float s[32];
#pragma unroll
  for (int jj = 0; jj < 32; ++jj) {
    const int j = g + (jj << 4);
    const int   a  = adjRow[j];
    const float ev = eRow[j];
    const float* kr = &Ksh[j * 20];
    const float4 k0 = *(const float4*)(kr);
    const float4 k1 = *(const float4*)(kr + 4);
    const float4 k2 = *(const float4*)(kr + 8);
    const float4 k3 = *(const float4*)(kr + 12);
    float sA = q0.x*k0.x, sB = q0.y*k0.y, sC = q0.z*k0.z, sD = q0.w*k0.w;
    sA = fmaf(q1.x,k1.x,sA); sB = fmaf(q1.y,k1.y,sB);
    sC = fmaf(q1.z,k1.z,sC); sD = fmaf(q1.w,k1.w,sD);
    sA = fmaf(q2.x,k2.x,sA); sB = fmaf(q2.y,k2.y,sB);
    sC = fmaf(q2.z,k2.z,sC); sD = fmaf(q2.w,k2.w,sD);
    sA = fmaf(q3.x,k3.x,sA); sB = fmaf(q3.y,k3.y,sB);
    sC = fmaf(q3.z,k3.z,sC); sD = fmaf(q3.w,k3.w,sD);
    const float sc = ((sA + sB) + (sC + sD) + ev * qw5 + qb5) * SCALE;
    s[jj] = (a == 0) ? NEG : sc;
  }

  // ---- row max: pairwise tree (all static indices) + 16-lane shfl --------
  float r16[16], r8[8], r4[4];
#pragma unroll
  for (int k = 0; k < 16; ++k) r16[k] = fmaxf(s[k], s[k + 16]);
#pragma unroll
  for (int k = 0; k < 8;  ++k) r8[k]  = fmaxf(r16[k], r16[k + 8]);
#pragma unroll
  for (int k = 0; k < 4;  ++k) r4[k]  = fmaxf(r8[k], r8[k + 4]);
  float M = fmaxf(fmaxf(r4[0], r4[1]), fmaxf(r4[2], r4[3]));
#pragma unroll
  for (int o = 1; o < 16; o <<= 1) M = fmaxf(M, __shfl_xor(M, o, 16));

  // ---- pass 2: independent exps + PV accumulation ------------------------
  float l0 = 0.f, l1 = 0.f, l2 = 0.f, l3 = 0.f;
  float acc[16];
#pragma unroll
  for (int d = 0; d < 16; ++d) acc[d] = 0.f;

#pragma unroll
  for (int jj = 0; jj < 32; ++jj) {
    const int j = g + (jj << 4);
    const float p = __expf(s[jj] - M);
    if      ((jj & 3) == 0) l0 += p;
    else if ((jj & 3) == 1) l1 += p;
    else if ((jj & 3) == 2) l2 += p;
    else                    l3 += p;
    const float* vr = &Vsh[j * 20];
    const float4 v0 = *(const float4*)(vr);
    const float4 v1 = *(const float4*)(vr + 4);
    const float4 v2 = *(const float4*)(vr + 8);
    const float4 v3 = *(const float4*)(vr + 12);
    acc[0]  = fmaf(p, v0.x, acc[0]);  acc[1]  = fmaf(p, v0.y, acc[1]);
    acc[2]  = fmaf(p, v0.z, acc[2]);  acc[3]  = fmaf(p, v0.w, acc[3]);
    acc[4]  = fmaf(p, v1.x, acc[4]);  acc[5]  = fmaf(p, v1.y, acc[5]);
    acc[6]  = fmaf(p, v1.z, acc[6]);  acc[7]  = fmaf(p, v1.w, acc[7]);
    acc[8]  = fmaf(p, v2.x, acc[8]);  acc[9]  = fmaf(p, v2.y, acc[9]);
    acc[10] = fmaf(p, v2.z, acc[10]); acc[11] = fmaf(p, v2.w, acc[11]);
    acc[12] = fmaf(p, v3.x, acc[12]); acc[13] = fmaf(p, v3.y, acc[13]);
    acc[14] = fmaf(p, v3.z, acc[14]); acc[15] = fmaf(p, v3.w, acc[15]);
  }

  float lw = (l0 + l1) + (l2 + l3);
#pragma unroll
  for (int o = 1; o < 16; o <<= 1) lw += __shfl_xor(lw, o, 16);

  // ---- transpose-reduce acc across the 16 g-threads via LDS --------------
  __syncthreads();                   // all Ksh/Vsh reads done
  float* P = Ksh;                    // [256 threads][stride 20]
  const int prow = (il * 16 + g) * 20;
  *(float4*)&P[prow +  0] = make_float4(acc[0],  acc[1],  acc[2],  acc[3]);
  *(float4*)&P[prow +  4] = make_float4(acc[4],  acc[5],  acc[6],  acc[7]);
  *(float4*)&P[prow +  8] = make_float4(acc[8],  acc[9],  acc[10], acc[11]);
  *(float4*)&P[prow + 12] = make_float4(acc[12], acc[13], acc[14], acc[15]);
  __syncthreads();

  float ssum = 0.f;
#pragma unroll
  for (int gp = 0; gp < 16; ++gp)
    ssum += P[(il * 16 + gp) * 20 + g];

  msg[((size_t)(b * N + i)) * HID + h * DH + g] = ssum * (1.0f / lw);
}

// ---------------------------------------------------------------------------
// Kernel C: out = LayerNorm(x + self_t + msg). One wave per row.
// ---------------------------------------------------------------------------
__global__ __launch_bounds__(256) void ln_kernel(
    const float* __restrict__ x, const float* __restrict__ ws,
    const float* __restrict__ gamma, const float* __restrict__ beta,
    float* __restrict__ out)
{
  const int t = threadIdx.x;
  const int lane = t & 63;
  const int row = blockIdx.x * 4 + (t >> 6);
  const size_t idx = (size_t)row * HID + lane;
  const float* ST  = ws + OFF_ST;
  const float* MSG = ws + OFF_MSG;

  const float v = x[idx] + ST[idx] + MSG[idx];
  float mu = v;
#pragma unroll
  for (int o = 1; o < 64; o <<= 1) mu += __shfl_xor(mu, o, 64);
  mu *= (1.0f / 64.0f);
  const float dv = v - mu;
  float var = dv * dv;
#pragma unroll
  for (int o = 1; o < 64; o <<= 1) var += __shfl_xor(var, o, 64);
  var *= (1.0f / 64.0f);
  out[idx] = dv * rsqrtf(var + LN_EPS) * gamma[lane] + beta[lane];
}

// ---------------------------------------------------------------------------
extern "C" void kernel_launch(void* const* d_in, const int* in_sizes, int n_in,
                              void* d_out, int out_size, void* d_ws, size_t ws_size,
                              hipStream_t stream)
{
  const float* x   = (const float*)d_in[0];
  const int*   adj = (const int*)d_in[1];
  const float* ef  = (const float*)d_in[2];
  const float* W1w = (const float*)d_in[3];
  const float* W1b = (const float*)d_in[4];
  const float* W2w = (const float*)d_in[5];
  const float* W2b = (const float*)d_in[6];
  const float* W3w = (const float*)d_in[7];
  const float* W3b = (const float*)d_in[8];
  const float* W4w = (const float*)d_in[9];
  const float* W4b = (const float*)d_in[10];
  const float* W5w = (const float*)d_in[11];
  const float* W5b = (const float*)d_in[12];
  const float* lng = (const float*)d_in[13];
  const float* lnb = (const float*)d_in[14];
  float* ws  = (float*)d_ws;
  float* out = (float*)d_out;

  proj_kernel<<<ROWS / 8, 256, 0, stream>>>(x, W1w, W1b, W2w, W2b, W3w, W3b, W4w, W4b, ws);
  attn_kernel<<<dim3(32, HEADS, B), 256, 0, stream>>>(adj, ef, W5w, W5b, ws);
  ln_kernel<<<ROWS / 4, 256, 0, stream>>>(x, ws, lng, lnb, out);
}